// Round 1
// baseline (9.894 us; speedup 1.0000x reference)
//
#include <hip/hip_runtime.h>

#define N_WIRES 10
#define N_LAYERS 6

// Analytic collapse of the QCNN circuit:
//   per layer k:  x_j <- prod_{i<=j} cos(x_i + theta_k[i])   (prefix product)
//   output     :  sigmoid(x @ W + b)
// Derivation: RX gates on a |0..0> product state compose to a product state;
// the adjacent-CNOT chain turns bit_j into prefix-XOR(b_0..b_j); independence
// gives <Z_j> = prod_{i<=j} cos(x_i + theta_i).

__global__ __launch_bounds__(64) void qcnn_kernel(
    const float* __restrict__ x_in,    // (B, 10)
    const float* __restrict__ thetas,  // (6, 10)
    const float* __restrict__ W,       // (10, 4)
    const float* __restrict__ bias,    // (4,)
    float* __restrict__ out,           // (B, 4)
    int B)
{
    int row = blockIdx.x * 64 + threadIdx.x;
    if (row >= B) return;

    float x[N_WIRES];
    // 40-byte rows are 8B-aligned -> five float2 loads
    const float2* p2 = reinterpret_cast<const float2*>(x_in + (size_t)row * N_WIRES);
    #pragma unroll
    for (int j = 0; j < 5; ++j) {
        float2 v = p2[j];
        x[2 * j]     = v.x;
        x[2 * j + 1] = v.y;
    }

    #pragma unroll
    for (int k = 0; k < N_LAYERS; ++k) {
        float p = 1.0f;
        #pragma unroll
        for (int j = 0; j < N_WIRES; ++j) {
            p *= __cosf(x[j] + thetas[k * N_WIRES + j]);  // uniform theta: L1 broadcast
            x[j] = p;                                      // x[j] (old) consumed before overwrite
        }
    }

    float acc0 = bias[0], acc1 = bias[1], acc2 = bias[2], acc3 = bias[3];
    #pragma unroll
    for (int j = 0; j < N_WIRES; ++j) {
        float4 w = *reinterpret_cast<const float4*>(W + j * 4);  // W rows are 16B-aligned
        acc0 = fmaf(x[j], w.x, acc0);
        acc1 = fmaf(x[j], w.y, acc1);
        acc2 = fmaf(x[j], w.z, acc2);
        acc3 = fmaf(x[j], w.w, acc3);
    }

    float4 o;
    o.x = 1.0f / (1.0f + __expf(-acc0));
    o.y = 1.0f / (1.0f + __expf(-acc1));
    o.z = 1.0f / (1.0f + __expf(-acc2));
    o.w = 1.0f / (1.0f + __expf(-acc3));
    *reinterpret_cast<float4*>(out + (size_t)row * 4) = o;  // 16B-aligned store
}

extern "C" void kernel_launch(void* const* d_in, const int* in_sizes, int n_in,
                              void* d_out, int out_size, void* d_ws, size_t ws_size,
                              hipStream_t stream) {
    const float* x      = (const float*)d_in[0];  // inputs (32768, 10)
    const float* thetas = (const float*)d_in[1];  // (6, 10)
    const float* W      = (const float*)d_in[2];  // (10, 4)
    const float* b      = (const float*)d_in[3];  // (4,)
    float* out          = (float*)d_out;          // (32768, 4)

    int B = in_sizes[0] / N_WIRES;
    int grid = (B + 63) / 64;
    qcnn_kernel<<<grid, 64, 0, stream>>>(x, thetas, W, b, out, B);
}

// Round 2
// 9.556 us; speedup vs baseline: 1.0354x; 1.0354x over previous
//
#include <hip/hip_runtime.h>

#define N_WIRES 10
#define N_LAYERS 6

// Analytic collapse of the QCNN circuit:
//   per layer k:  x_j <- prod_{i<=j} cos(x_i + theta_k[i])   (prefix product)
//   output     :  sigmoid(x @ W + b)
// Derivation: RX gates on |0..0> keep a product state (RX's commute across
// wires, compose on a wire); the adjacent-CNOT chain makes bit_j the
// prefix-XOR of b_0..b_j; bit independence gives <Z_j> = prod_{i<=j} cos(phi_i).
//
// Structure note: within a layer, all 10 cos() args depend only on the
// PREVIOUS layer's outputs, so the 10 v_cos_f32 issue independently
// (TRANS-pipe ILP); only the 10-multiply prefix chain is serial.

__global__ __launch_bounds__(256) void qcnn_kernel(
    const float* __restrict__ x_in,    // (B, 10)
    const float* __restrict__ thetas,  // (6, 10)
    const float* __restrict__ W,       // (10, 4)
    const float* __restrict__ bias,    // (4,)
    float* __restrict__ out,           // (B, 4)
    int B)
{
    int row = blockIdx.x * 256 + threadIdx.x;
    if (row >= B) return;

    float x[N_WIRES];
    // 40-byte rows are 8B-aligned -> five float2 loads
    const float2* p2 = reinterpret_cast<const float2*>(x_in + (size_t)row * N_WIRES);
    #pragma unroll
    for (int j = 0; j < 5; ++j) {
        float2 v = p2[j];
        x[2 * j]     = v.x;
        x[2 * j + 1] = v.y;
    }

    #pragma unroll
    for (int k = 0; k < N_LAYERS; ++k) {
        float c[N_WIRES];
        // all 10 cosines independent -> back-to-back TRANS issue
        #pragma unroll
        for (int j = 0; j < N_WIRES; ++j)
            c[j] = __cosf(x[j] + thetas[k * N_WIRES + j]);  // theta: scalar (s_load) broadcast
        // short serial prefix-product chain
        float p = c[0];
        x[0] = p;
        #pragma unroll
        for (int j = 1; j < N_WIRES; ++j) {
            p *= c[j];
            x[j] = p;
        }
    }

    float acc0 = bias[0], acc1 = bias[1], acc2 = bias[2], acc3 = bias[3];
    #pragma unroll
    for (int j = 0; j < N_WIRES; ++j) {
        float4 w = *reinterpret_cast<const float4*>(W + j * 4);  // 16B-aligned rows
        acc0 = fmaf(x[j], w.x, acc0);
        acc1 = fmaf(x[j], w.y, acc1);
        acc2 = fmaf(x[j], w.z, acc2);
        acc3 = fmaf(x[j], w.w, acc3);
    }

    float4 o;
    o.x = 1.0f / (1.0f + __expf(-acc0));
    o.y = 1.0f / (1.0f + __expf(-acc1));
    o.z = 1.0f / (1.0f + __expf(-acc2));
    o.w = 1.0f / (1.0f + __expf(-acc3));
    *reinterpret_cast<float4*>(out + (size_t)row * 4) = o;  // 16B-aligned store
}

extern "C" void kernel_launch(void* const* d_in, const int* in_sizes, int n_in,
                              void* d_out, int out_size, void* d_ws, size_t ws_size,
                              hipStream_t stream) {
    const float* x      = (const float*)d_in[0];  // (32768, 10)
    const float* thetas = (const float*)d_in[1];  // (6, 10)
    const float* W      = (const float*)d_in[2];  // (10, 4)
    const float* b      = (const float*)d_in[3];  // (4,)
    float* out          = (float*)d_out;          // (32768, 4)

    int B = in_sizes[0] / N_WIRES;
    int grid = (B + 255) / 256;
    qcnn_kernel<<<grid, 256, 0, stream>>>(x, thetas, W, b, out, B);
}